// Round 12
// baseline (78.666 us; speedup 1.0000x reference)
//
#include <hip/hip_runtime.h>
#include <hip/hip_bf16.h>

#define DIM   1024
#define SEQL  4096
#define NTOK  16384
#define NATT  90
#define NATTP 96

typedef __attribute__((ext_vector_type(8))) short frag_ab;   // 8 x bf16
typedef __attribute__((ext_vector_type(4))) float frag_cd;   // 4 x f32
typedef __attribute__((ext_vector_type(16))) float f32x16;   // 32x32 accumulator

typedef unsigned int u32;
typedef const __attribute__((address_space(1))) u32* gp_t;
typedef __attribute__((address_space(3))) u32* lp_t;

static __device__ __forceinline__ unsigned short f2bf(float f) {
    unsigned int u = __float_as_uint(f);
    return (unsigned short)((u + 0x7fffu + ((u >> 16) & 1u)) >> 16);  // RNE
}
static __device__ __forceinline__ ushort4 f4tobf(float4 v) {
    ushort4 r; r.x = f2bf(v.x); r.y = f2bf(v.y); r.z = f2bf(v.z); r.w = f2bf(v.w);
    return r;
}
static __device__ __forceinline__ float4 bf4tof(ushort4 u) {
    float4 r;
    r.x = __uint_as_float((u32)u.x << 16);
    r.y = __uint_as_float((u32)u.y << 16);
    r.z = __uint_as_float((u32)u.z << 16);
    r.w = __uint_as_float((u32)u.w << 16);
    return r;
}

// ---------- cvt: wo -> bf16 (1024 blocks) + w2 -> fragment-packed bf16 (48 blocks) ----
__global__ __launch_bounds__(256) void cvt_kernel(
    const float* __restrict__ w2, const float* __restrict__ wo,
    unsigned short* __restrict__ w2p, unsigned short* __restrict__ wob)
{
    const int bid = blockIdx.x;
    if (bid < 1024) {
        const int i = bid * 256 + threadIdx.x;
        float4 v = ((const float4*)wo)[i];
        *(ushort4*)(wob + (size_t)i * 4) = f4tobf(v);
    } else {
        const int idx = (bid - 1024) * 256 + threadIdx.x;   // 0..12287
        const int c    = idx / 384;
        const int rem  = idx - c * 384;
        const int f    = rem >> 6;
        const int lane = rem & 63;
        const int row  = f * 16 + (lane & 15);
        const int col  = c * 32 + (lane >> 4) * 8;
        float4 v0 = make_float4(0.f, 0.f, 0.f, 0.f), v1 = v0;
        if (row < NATT) {
            v0 = *(const float4*)(w2 + (size_t)row * DIM + col);
            v1 = *(const float4*)(w2 + (size_t)row * DIM + col + 4);
        }
        unsigned short* dst = w2p + (size_t)idx * 8;
        *(ushort4*)(dst)     = f4tobf(v0);
        *(ushort4*)(dst + 4) = f4tobf(v1);
    }
}

// ---------- fused stage 1+2: att -> coeff (LDS) -> y stencil (from LDS xs) -> ybf ----
#define ATOK 16
#define PSTR 98

__global__ __launch_bounds__(256) void att_y_kernel(
    const float* __restrict__ x, const unsigned short* __restrict__ w2p,
    const float* __restrict__ b2, unsigned short* __restrict__ ybf)
{
    __shared__ __align__(16) unsigned short xs[ATOK * 1024];  // 32 KB, chunk-swizzled
    __shared__ float part[2 * ATOK * PSTR];                   // 12.25 KB
    __shared__ float summ[ATOK * NATTP];                      // 6 KB
    __shared__ float b2s[NATTP];
    __shared__ float coe[ATOK][12];

    const int tid  = threadIdx.x;
    const int wave = tid >> 6, lane = tid & 63;
    const int fr = lane & 15, kq = lane >> 4;
    const int bid = blockIdx.x;
    const int lid = (bid & 7) * 128 + (bid >> 3);   // bijective XCD swizzle
    const int tok0 = lid * ATOK;
    const int bb = tok0 >> 12;
    const int l0 = tok0 & 4095;

    if (tid < NATTP) b2s[tid] = (tid < NATT) ? b2[tid] : 0.f;

    #pragma unroll
    for (int t = 0; t < 4; ++t) {
        const int row = t * 4 + wave;
        const float4* xr = (const float4*)(x + (size_t)(tok0 + row) * DIM);
        #pragma unroll
        for (int tt = 0; tt < 4; ++tt) {
            const int c4 = tt * 64 + lane;
            float4 v = xr[c4];
            const int ch = c4 >> 1, half = c4 & 1;
            *(ushort4*)(&xs[row * 1024 + ((ch ^ (row & 7)) * 8 + half * 4)]) = f4tobf(v);
        }
    }

    const float4 z4 = make_float4(0.f, 0.f, 0.f, 0.f);
    float4 halo[8];
    #pragma unroll
    for (int hh = 0; hh < 8; ++hh) {
        const int off = (hh < 4) ? (hh - 4) : (hh + 12);
        const int src = l0 + off;
        halo[hh] = z4;
        if (src >= 0 && src < SEQL)
            halo[hh] = *((const float4*)(x + ((size_t)bb * SEQL + src) * DIM) + tid);
    }
    __syncthreads();

    frag_cd acc[6] = {};
    #pragma unroll
    for (int kk = 0; kk < 8; ++kk) {
        const int ch = wave * 32 + kk * 4 + kq;
        frag_ab a = *(const frag_ab*)(&xs[fr * 1024 + ((ch ^ (fr & 7)) * 8)]);
        const int c = wave * 8 + kk;
        #pragma unroll
        for (int f = 0; f < 6; ++f) {
            frag_ab b = *(const frag_ab*)(w2p + ((size_t)((c * 6 + f) * 64) + lane) * 8);
            acc[f] = __builtin_amdgcn_mfma_f32_16x16x32_bf16(a, b, acc[f], 0, 0, 0);
        }
    }

    const int col = lane & 15, rb = (lane >> 4) * 4;
    float* myp = &part[(wave & 1) * ATOK * PSTR];
    if (wave < 2) {
        #pragma unroll
        for (int f = 0; f < 6; ++f)
            #pragma unroll
            for (int r = 0; r < 4; ++r)
                myp[(rb + r) * PSTR + f * 16 + col] = acc[f][r];
    }
    __syncthreads();
    if (wave >= 2) {
        #pragma unroll
        for (int f = 0; f < 6; ++f)
            #pragma unroll
            for (int r = 0; r < 4; ++r)
                myp[(rb + r) * PSTR + f * 16 + col] += acc[f][r];
    }
    __syncthreads();

    for (int o = tid; o < ATOK * NATTP; o += 256) {
        const int t = o / NATTP, m = o - (o / NATTP) * NATTP;
        summ[o] = b2s[m] + part[t * PSTR + m] + part[ATOK * PSTR + t * PSTR + m];
    }
    __syncthreads();

    if (tid < 160) {
        const int t = tid / 10, j = tid - (tid / 10) * 10;
        float s = 0.f;
        if (j < 9) {
            #pragma unroll
            for (int jj = 0; jj < 9; ++jj) s += sinf(summ[t * NATTP + j * 9 + jj]);
        } else {
            #pragma unroll
            for (int m = NATT - 9; m < NATT; ++m) s += summ[t * NATTP + m];
        }
        coe[t][j] = s;
    }
    __syncthreads();

    const int ch2 = tid >> 1, hf2 = tid & 1;
    auto rowval = [&](int rel) -> float4 {
        if (rel < 0)  return halo[rel + 4];
        if (rel > 15) return halo[rel - 12];
        ushort4 u = *(const ushort4*)(&xs[rel * 1024 + ((ch2 ^ (rel & 7)) * 8 + hf2 * 4)]);
        return bf4tof(u);
    };

    float4 w[9];
    #pragma unroll
    for (int k = 0; k < 8; ++k) w[k] = rowval(k - 4);

    #pragma unroll
    for (int t = 0; t < ATOK; ++t) {
        w[8] = rowval(t + 4);
        float4 a4;
        a4.x = a4.y = a4.z = a4.w = coe[t][9];
        #pragma unroll
        for (int k = 0; k < 9; ++k) {
            const float ck = coe[t][k];
            a4.x += ck * w[k].x; a4.y += ck * w[k].y;
            a4.z += ck * w[k].z; a4.w += ck * w[k].w;
        }
        *(ushort4*)(ybf + (size_t)(tok0 + t) * DIM + tid * 4) = f4tobf(a4);
        #pragma unroll
        for (int k = 0; k < 8; ++k) w[k] = w[k + 1];
    }
}

// ---------- stage 3: out = y @ wo^T + bo ----------
// 256x256 tile, BK=64, 8 waves (2Mx4N), double-buffered LDS, counted vmcnt.
// R5 schedule + layout (42.4 us, conflicts 0), MFMA shape switched to
// 32x32x16 (half the instructions, same LDS bytes, ~17% less matrix-pipe).
#define GBM 256
#define GBN 256
#define GBK 64

#define STAGE(d, kt)                                                           \
    {                                                                          \
        const int kc_ = (kt) * GBK;                                            \
        _Pragma("unroll")                                                      \
        for (int j_ = 0; j_ < 4; ++j_) {                                       \
            __builtin_amdgcn_global_load_lds(                                  \
                (gp_t)(A + (size_t)(m0 + srow[j_]) * DIM + kc_ + scol[j_]),    \
                (lp_t)(&As[d][(wave * 4 + j_) * 512]), 16, 0, 0);              \
            __builtin_amdgcn_global_load_lds(                                  \
                (gp_t)(Bm + (size_t)(n0 + srow[j_]) * DIM + kc_ + scol[j_]),   \
                (lp_t)(&Bs[d][(wave * 4 + j_) * 512]), 16, 0, 0);              \
        }                                                                      \
    }

// frag read: row-major [256][64] bf16, 16B chunk p holds global chunk p^(row&7)
#define RDB32(d_, ni_, ks_) \
    (*(const frag_ab*)(&Bs[d_][(wn + (ni_) * 32 + l31) * 64 + (((2 * (ks_) + l5) ^ ((wn + (ni_) * 32 + l31) & 7)) * 8)]))
#define RDA32(d_, mi_, ks_) \
    (*(const frag_ab*)(&As[d_][(wm + (mi_) * 32 + l31) * 64 + (((2 * (ks_) + l5) ^ ((wm + (mi_) * 32 + l31) & 7)) * 8)]))

__global__ __launch_bounds__(512, 2) void gemm_kernel(
    const unsigned short* __restrict__ A,   // y_bf  [16384][1024]
    const unsigned short* __restrict__ Bm,  // wo_bf [1024][1024] (row = out col)
    const float* __restrict__ bo,
    float* __restrict__ out)
{
    __shared__ unsigned short As[2][GBM * GBK];   // 2 x 32 KB
    __shared__ unsigned short Bs[2][GBN * GBK];   // 2 x 32 KB

    const int tid  = threadIdx.x;
    const int wave = tid >> 6, lane = tid & 63;
    const int l31 = lane & 31, l5 = lane >> 5;
    const int wm = (wave >> 2) * 128;    // 0 or 128
    const int wn = (wave & 3) * 64;      // 0,64,128,192

    // bijective XCD swizzle: 256 blocks = 8 XCDs x 32; XCD owns 8 contiguous M-panels
    const int bid = blockIdx.x;
    const int lid = (bid & 7) * 32 + (bid >> 3);
    const int m0  = (lid >> 2) * GBM;
    const int n0  = (lid & 3) * GBN;

    int srow[4], scol[4];
    #pragma unroll
    for (int j = 0; j < 4; ++j) {
        int ci = (wave * 4 + j) * 64 + lane;
        int row = ci >> 3;
        srow[j] = row;
        scol[j] = ((ci & 7) ^ (row & 7)) * 8;    // pre-swizzled global source
    }

    f32x16 acc[4][2] = {};   // [mi][ni] 32x32 frags: wave output 128x64

    STAGE(0, 0);
    STAGE(1, 1);

    for (int kt = 0; kt < 15; ++kt) {
        const int d = kt & 1;
        asm volatile("s_waitcnt vmcnt(8)" ::: "memory");   // kt landed; kt+1 in flight
        __builtin_amdgcn_s_barrier();

        // ---- cluster 1: k-half 0 (ks 0,1) ----
        frag_ab b0[2][2], a0[4][2];
        #pragma unroll
        for (int ni = 0; ni < 2; ++ni)
            #pragma unroll
            for (int ks = 0; ks < 2; ++ks) b0[ni][ks] = RDB32(d, ni, ks);
        #pragma unroll
        for (int mi = 0; mi < 4; ++mi)
            #pragma unroll
            for (int ks = 0; ks < 2; ++ks) a0[mi][ks] = RDA32(d, mi, ks);
        __builtin_amdgcn_s_setprio(1);
        #pragma unroll
        for (int mi = 0; mi < 4; ++mi)
            #pragma unroll
            for (int ni = 0; ni < 2; ++ni) {
                acc[mi][ni] = __builtin_amdgcn_mfma_f32_32x32x16_bf16(a0[mi][0], b0[ni][0], acc[mi][ni], 0, 0, 0);
                acc[mi][ni] = __builtin_amdgcn_mfma_f32_32x32x16_bf16(a0[mi][1], b0[ni][1], acc[mi][ni], 0, 0, 0);
            }
        __builtin_amdgcn_s_setprio(0);

        // ---- cluster 2: k-half 1 (ks 2,3) ----
        frag_ab b1[2][2], a1[4][2];
        #pragma unroll
        for (int ni = 0; ni < 2; ++ni)
            #pragma unroll
            for (int ks = 0; ks < 2; ++ks) b1[ni][ks] = RDB32(d, ni, ks + 2);
        #pragma unroll
        for (int mi = 0; mi < 4; ++mi)
            #pragma unroll
            for (int ks = 0; ks < 2; ++ks) a1[mi][ks] = RDA32(d, mi, ks + 2);
        asm volatile("s_waitcnt lgkmcnt(0)" ::: "memory"); // all reads of buf d done
        __builtin_amdgcn_s_barrier();                      // ... across all waves
        if (kt < 14) { STAGE(d, kt + 2); }                 // refill buf d
        __builtin_amdgcn_s_setprio(1);
        #pragma unroll
        for (int mi = 0; mi < 4; ++mi)
            #pragma unroll
            for (int ni = 0; ni < 2; ++ni) {
                acc[mi][ni] = __builtin_amdgcn_mfma_f32_32x32x16_bf16(a1[mi][0], b1[ni][0], acc[mi][ni], 0, 0, 0);
                acc[mi][ni] = __builtin_amdgcn_mfma_f32_32x32x16_bf16(a1[mi][1], b1[ni][1], acc[mi][ni], 0, 0, 0);
            }
        __builtin_amdgcn_s_setprio(0);
    }

    // peeled last K-tile (kt = 15, buffer 1): drain fully
    {
        asm volatile("s_waitcnt vmcnt(0)" ::: "memory");
        __builtin_amdgcn_s_barrier();
        #pragma unroll
        for (int h = 0; h < 2; ++h) {
            frag_ab bt[2][2], at[4][2];
            #pragma unroll
            for (int ni = 0; ni < 2; ++ni)
                #pragma unroll
                for (int ks = 0; ks < 2; ++ks) bt[ni][ks] = RDB32(1, ni, ks + h * 2);
            #pragma unroll
            for (int mi = 0; mi < 4; ++mi)
                #pragma unroll
                for (int ks = 0; ks < 2; ++ks) at[mi][ks] = RDA32(1, mi, ks + h * 2);
            __builtin_amdgcn_s_setprio(1);
            #pragma unroll
            for (int mi = 0; mi < 4; ++mi)
                #pragma unroll
                for (int ni = 0; ni < 2; ++ni) {
                    acc[mi][ni] = __builtin_amdgcn_mfma_f32_32x32x16_bf16(at[mi][0], bt[ni][0], acc[mi][ni], 0, 0, 0);
                    acc[mi][ni] = __builtin_amdgcn_mfma_f32_32x32x16_bf16(at[mi][1], bt[ni][1], acc[mi][ni], 0, 0, 0);
                }
            __builtin_amdgcn_s_setprio(0);
        }
    }

    // epilogue: 32x32 C/D layout col=lane&31, row=(r&3)+8*(r>>2)+4*(lane>>5)
    #pragma unroll
    for (int ni = 0; ni < 2; ++ni) {
        const int col = n0 + wn + ni * 32 + l31;
        const float bias = bo[col];
        #pragma unroll
        for (int mi = 0; mi < 4; ++mi) {
            #pragma unroll
            for (int r = 0; r < 16; ++r) {
                const int row = m0 + wm + mi * 32 + (r & 3) + 8 * (r >> 2) + 4 * l5;
                out[(size_t)row * DIM + col] = acc[mi][ni][r] + bias;
            }
        }
    }
}

// ---------- launch ----------
extern "C" void kernel_launch(void* const* d_in, const int* in_sizes, int n_in,
                              void* d_out, int out_size, void* d_ws, size_t ws_size,
                              hipStream_t stream) {
    const float* x  = (const float*)d_in[0];
    const float* w2 = (const float*)d_in[1];
    const float* b2 = (const float*)d_in[2];
    const float* wo = (const float*)d_in[3];
    const float* bo = (const float*)d_in[4];
    float* out = (float*)d_out;

    char* ws = (char*)d_ws;
    unsigned short* wob = (unsigned short*)ws;                       // 2 MB
    unsigned short* ybf = (unsigned short*)(ws + 2097152);           // 32 MB
    unsigned short* w2p = (unsigned short*)(ws + 2097152 + 33554432);// 192 KB

    cvt_kernel<<<1024 + 48, 256, 0, stream>>>(w2, wo, w2p, wob);
    att_y_kernel<<<NTOK / ATOK, 256, 0, stream>>>(x, w2p, b2, ybf);
    gemm_kernel<<<NTOK / GBM * (DIM / GBN), 512, 0, stream>>>(ybf, wob, bo, out);
}

// Round 14
// 75.997 us; speedup vs baseline: 1.0351x; 1.0351x over previous
//
#include <hip/hip_runtime.h>
#include <hip/hip_bf16.h>

#define DIM   1024
#define SEQL  4096
#define NTOK  16384
#define NATT  90
#define NATTP 96

typedef __attribute__((ext_vector_type(8))) short frag_ab;   // 8 x bf16
typedef __attribute__((ext_vector_type(4))) float frag_cd;   // 4 x f32

typedef unsigned int u32;
typedef const __attribute__((address_space(1))) u32* gp_t;
typedef __attribute__((address_space(3))) u32* lp_t;

static __device__ __forceinline__ unsigned short f2bf(float f) {
    unsigned int u = __float_as_uint(f);
    return (unsigned short)((u + 0x7fffu + ((u >> 16) & 1u)) >> 16);  // RNE
}
static __device__ __forceinline__ ushort4 f4tobf(float4 v) {
    ushort4 r; r.x = f2bf(v.x); r.y = f2bf(v.y); r.z = f2bf(v.z); r.w = f2bf(v.w);
    return r;
}
static __device__ __forceinline__ float4 bf4tof(ushort4 u) {
    float4 r;
    r.x = __uint_as_float((u32)u.x << 16);
    r.y = __uint_as_float((u32)u.y << 16);
    r.z = __uint_as_float((u32)u.z << 16);
    r.w = __uint_as_float((u32)u.w << 16);
    return r;
}

// ---------- w2 -> fragment-packed bf16 (48 blocks; must precede att_y) ----------
__global__ __launch_bounds__(256) void cvt_w2_kernel(
    const float* __restrict__ w2, unsigned short* __restrict__ w2p)
{
    const int idx = blockIdx.x * 256 + threadIdx.x;   // 0..12287
    const int c    = idx / 384;
    const int rem  = idx - c * 384;
    const int f    = rem >> 6;
    const int lane = rem & 63;
    const int row  = f * 16 + (lane & 15);
    const int col  = c * 32 + (lane >> 4) * 8;
    float4 v0 = make_float4(0.f, 0.f, 0.f, 0.f), v1 = v0;
    if (row < NATT) {
        v0 = *(const float4*)(w2 + (size_t)row * DIM + col);
        v1 = *(const float4*)(w2 + (size_t)row * DIM + col + 4);
    }
    unsigned short* dst = w2p + (size_t)idx * 8;
    *(ushort4*)(dst)     = f4tobf(v0);
    *(ushort4*)(dst + 4) = f4tobf(v1);
}

// ---------- fused: att -> coeff -> y stencil -> ybf  (+ wo cvt on blocks >= 1024) ----
#define ATOK 16
#define PSTR 98

__global__ __launch_bounds__(256) void att_y_kernel(
    const float* __restrict__ x, const unsigned short* __restrict__ w2p,
    const float* __restrict__ b2, const float* __restrict__ wo,
    unsigned short* __restrict__ ybf, unsigned short* __restrict__ wob)
{
    __shared__ __align__(16) unsigned short xs[ATOK * 1024];  // 32 KB, chunk-swizzled
    __shared__ float part[2 * ATOK * PSTR];                   // 12.25 KB
    __shared__ float summ[ATOK * NATTP];                      // 6 KB
    __shared__ float b2s[NATTP];
    __shared__ float coe[ATOK][12];

    const int tid  = threadIdx.x;
    const int bid = blockIdx.x;

    if (bid >= 1024) {
        // wo -> bf16 (consumed only by gemm, launched after us).
        // Exactly ONE float4 per thread: 1024 blocks x 256 thr = 262144 = 1024*1024/4.
        const int i = (bid - 1024) * 256 + tid;
        float4 v = ((const float4*)wo)[i];
        *(ushort4*)(wob + (size_t)i * 4) = f4tobf(v);
        return;
    }

    const int wave = tid >> 6, lane = tid & 63;
    const int fr = lane & 15, kq = lane >> 4;
    const int lid = (bid & 7) * 128 + (bid >> 3);   // bijective XCD swizzle
    const int tok0 = lid * ATOK;
    const int bb = tok0 >> 12;
    const int l0 = tok0 & 4095;

    if (tid < NATTP) b2s[tid] = (tid < NATT) ? b2[tid] : 0.f;

    // stage x: each wave loads 4 full rows coalesced, swizzled bf16 store.
    #pragma unroll
    for (int t = 0; t < 4; ++t) {
        const int row = t * 4 + wave;
        const float4* xr = (const float4*)(x + (size_t)(tok0 + row) * DIM);
        #pragma unroll
        for (int tt = 0; tt < 4; ++tt) {
            const int c4 = tt * 64 + lane;
            float4 v = xr[c4];
            const int ch = c4 >> 1, half = c4 & 1;
            *(ushort4*)(&xs[row * 1024 + ((ch ^ (row & 7)) * 8 + half * 4)]) = f4tobf(v);
        }
    }

    // halo loads issued early; mostly XCD-L2 hits after swizzle.
    const float4 z4 = make_float4(0.f, 0.f, 0.f, 0.f);
    float4 halo[8];
    #pragma unroll
    for (int hh = 0; hh < 8; ++hh) {
        const int off = (hh < 4) ? (hh - 4) : (hh + 12);
        const int src = l0 + off;
        halo[hh] = z4;
        if (src >= 0 && src < SEQL)
            halo[hh] = *((const float4*)(x + ((size_t)bb * SEQL + src) * DIM) + tid);
    }
    __syncthreads();

    // MFMA: wave w owns K chunk-range [w*256, w*256+256)
    frag_cd acc[6] = {};
    #pragma unroll
    for (int kk = 0; kk < 8; ++kk) {
        const int ch = wave * 32 + kk * 4 + kq;
        frag_ab a = *(const frag_ab*)(&xs[fr * 1024 + ((ch ^ (fr & 7)) * 8)]);
        const int c = wave * 8 + kk;
        #pragma unroll
        for (int f = 0; f < 6; ++f) {
            frag_ab b = *(const frag_ab*)(w2p + ((size_t)((c * 6 + f) * 64) + lane) * 8);
            acc[f] = __builtin_amdgcn_mfma_f32_16x16x32_bf16(a, b, acc[f], 0, 0, 0);
        }
    }

    // two-step cross-wave partial reduction
    const int col = lane & 15, rb = (lane >> 4) * 4;
    float* myp = &part[(wave & 1) * ATOK * PSTR];
    if (wave < 2) {
        #pragma unroll
        for (int f = 0; f < 6; ++f)
            #pragma unroll
            for (int r = 0; r < 4; ++r)
                myp[(rb + r) * PSTR + f * 16 + col] = acc[f][r];
    }
    __syncthreads();
    if (wave >= 2) {
        #pragma unroll
        for (int f = 0; f < 6; ++f)
            #pragma unroll
            for (int r = 0; r < 4; ++r)
                myp[(rb + r) * PSTR + f * 16 + col] += acc[f][r];
    }
    __syncthreads();

    for (int o = tid; o < ATOK * NATTP; o += 256) {
        const int t = o / NATTP, m = o - (o / NATTP) * NATTP;
        summ[o] = b2s[m] + part[t * PSTR + m] + part[ATOK * PSTR + t * PSTR + m];
    }
    __syncthreads();

    // coeff[k] = sum_j sin(att[9k+j]);  absum = sum att[81..89]
    if (tid < 160) {
        const int t = tid / 10, j = tid - (tid / 10) * 10;
        float s = 0.f;
        if (j < 9) {
            #pragma unroll
            for (int jj = 0; jj < 9; ++jj) s += sinf(summ[t * NATTP + j * 9 + jj]);
        } else {
            #pragma unroll
            for (int m = NATT - 9; m < NATT; ++m) s += summ[t * NATTP + m];
        }
        coe[t][j] = s;
    }
    __syncthreads();

    // y phase: rolling window; interior rows from LDS xs, halo from regs
    const int ch2 = tid >> 1, hf2 = tid & 1;
    auto rowval = [&](int rel) -> float4 {
        if (rel < 0)  return halo[rel + 4];
        if (rel > 15) return halo[rel - 12];
        ushort4 u = *(const ushort4*)(&xs[rel * 1024 + ((ch2 ^ (rel & 7)) * 8 + hf2 * 4)]);
        return bf4tof(u);
    };

    float4 w[9];
    #pragma unroll
    for (int k = 0; k < 8; ++k) w[k] = rowval(k - 4);

    #pragma unroll
    for (int t = 0; t < ATOK; ++t) {
        w[8] = rowval(t + 4);
        float4 a4;
        a4.x = a4.y = a4.z = a4.w = coe[t][9];
        #pragma unroll
        for (int k = 0; k < 9; ++k) {
            const float ck = coe[t][k];
            a4.x += ck * w[k].x; a4.y += ck * w[k].y;
            a4.z += ck * w[k].z; a4.w += ck * w[k].w;
        }
        *(ushort4*)(ybf + (size_t)(tok0 + t) * DIM + tid * 4) = f4tobf(a4);
        #pragma unroll
        for (int k = 0; k < 8; ++k) w[k] = w[k + 1];
    }
}

// ---------- stage 3: out = y @ wo^T + bo ----------
// 256x256 tile, BK=64, 8 waves (2Mx4N), double-buffered LDS, counted vmcnt.
// FINAL — R5 structure, measured 42.4 us (811 TF), conflicts 0. Five variants
// tried (R6/R8/R10 schedules, R12 32x32 shape) all regressed. Do not touch.
#define GBM 256
#define GBN 256
#define GBK 64

#define STAGE(d, kt)                                                           \
    {                                                                          \
        const int kc_ = (kt) * GBK;                                            \
        _Pragma("unroll")                                                      \
        for (int j_ = 0; j_ < 4; ++j_) {                                       \
            __builtin_amdgcn_global_load_lds(                                  \
                (gp_t)(A + (size_t)(m0 + srow[j_]) * DIM + kc_ + scol[j_]),    \
                (lp_t)(&As[d][(wave * 4 + j_) * 512]), 16, 0, 0);              \
            __builtin_amdgcn_global_load_lds(                                  \
                (gp_t)(Bm + (size_t)(n0 + srow[j_]) * DIM + kc_ + scol[j_]),   \
                (lp_t)(&Bs[d][(wave * 4 + j_) * 512]), 16, 0, 0);              \
        }                                                                      \
    }

__global__ __launch_bounds__(512, 2) void gemm_kernel(
    const unsigned short* __restrict__ A,   // y_bf  [16384][1024]
    const unsigned short* __restrict__ Bm,  // wo_bf [1024][1024] (row = out col)
    const float* __restrict__ bo,
    float* __restrict__ out)
{
    __shared__ unsigned short As[2][GBM * GBK];   // 2 x 32 KB
    __shared__ unsigned short Bs[2][GBN * GBK];   // 2 x 32 KB

    const int tid  = threadIdx.x;
    const int wave = tid >> 6, lane = tid & 63;
    const int fr = lane & 15, kq = lane >> 4;
    const int wm = (wave >> 2) * 128;    // 0 or 128
    const int wn = (wave & 3) * 64;      // 0,64,128,192

    // bijective XCD swizzle: 256 blocks = 8 XCDs x 32; XCD owns 8 contiguous M-panels
    const int bid = blockIdx.x;
    const int lid = (bid & 7) * 32 + (bid >> 3);
    const int m0  = (lid >> 2) * GBM;
    const int n0  = (lid & 3) * GBN;

    int srow[4], scol[4];
    #pragma unroll
    for (int j = 0; j < 4; ++j) {
        int ci = (wave * 4 + j) * 64 + lane;
        int row = ci >> 3;
        srow[j] = row;
        scol[j] = ((ci & 7) ^ (row & 7)) * 8;    // pre-swizzled global source
    }

    frag_cd acc[8][4] = {};

    STAGE(0, 0);
    STAGE(1, 1);

    for (int kt = 0; kt < 15; ++kt) {
        const int d = kt & 1;
        asm volatile("s_waitcnt vmcnt(8)" ::: "memory");   // kt landed; kt+1 in flight
        __builtin_amdgcn_s_barrier();

        frag_ab b0[4], b1[4];
        #pragma unroll
        for (int ni = 0; ni < 4; ++ni) {
            int row = wn + ni * 16 + fr;
            b0[ni] = *(const frag_ab*)(&Bs[d][row * 64 + ((kq       ^ (row & 7)) * 8)]);
            b1[ni] = *(const frag_ab*)(&Bs[d][row * 64 + (((4 + kq) ^ (row & 7)) * 8)]);
        }
        frag_ab alo0[4], alo1[4];
        #pragma unroll
        for (int mi = 0; mi < 4; ++mi) {
            int row = wm + mi * 16 + fr;
            alo0[mi] = *(const frag_ab*)(&As[d][row * 64 + ((kq       ^ (row & 7)) * 8)]);
            alo1[mi] = *(const frag_ab*)(&As[d][row * 64 + (((4 + kq) ^ (row & 7)) * 8)]);
        }
        __builtin_amdgcn_s_setprio(1);
        #pragma unroll
        for (int mi = 0; mi < 4; ++mi)
            #pragma unroll
            for (int ni = 0; ni < 4; ++ni) {
                acc[mi][ni] = __builtin_amdgcn_mfma_f32_16x16x32_bf16(alo0[mi], b0[ni], acc[mi][ni], 0, 0, 0);
                acc[mi][ni] = __builtin_amdgcn_mfma_f32_16x16x32_bf16(alo1[mi], b1[ni], acc[mi][ni], 0, 0, 0);
            }
        __builtin_amdgcn_s_setprio(0);
        frag_ab ahi0[4], ahi1[4];
        #pragma unroll
        for (int mi = 0; mi < 4; ++mi) {
            int row = wm + (mi + 4) * 16 + fr;
            ahi0[mi] = *(const frag_ab*)(&As[d][row * 64 + ((kq       ^ (row & 7)) * 8)]);
            ahi1[mi] = *(const frag_ab*)(&As[d][row * 64 + (((4 + kq) ^ (row & 7)) * 8)]);
        }
        asm volatile("s_waitcnt lgkmcnt(0)" ::: "memory");
        __builtin_amdgcn_s_barrier();
        if (kt < 14) { STAGE(d, kt + 2); }
        __builtin_amdgcn_s_setprio(1);
        #pragma unroll
        for (int mi = 0; mi < 4; ++mi)
            #pragma unroll
            for (int ni = 0; ni < 4; ++ni) {
                acc[mi + 4][ni] = __builtin_amdgcn_mfma_f32_16x16x32_bf16(ahi0[mi], b0[ni], acc[mi + 4][ni], 0, 0, 0);
                acc[mi + 4][ni] = __builtin_amdgcn_mfma_f32_16x16x32_bf16(ahi1[mi], b1[ni], acc[mi + 4][ni], 0, 0, 0);
            }
        __builtin_amdgcn_s_setprio(0);
    }

    {
        asm volatile("s_waitcnt vmcnt(0)" ::: "memory");
        __builtin_amdgcn_s_barrier();
        frag_ab b0[4], b1[4];
        #pragma unroll
        for (int ni = 0; ni < 4; ++ni) {
            int row = wn + ni * 16 + fr;
            b0[ni] = *(const frag_ab*)(&Bs[1][row * 64 + ((kq       ^ (row & 7)) * 8)]);
            b1[ni] = *(const frag_ab*)(&Bs[1][row * 64 + (((4 + kq) ^ (row & 7)) * 8)]);
        }
        #pragma unroll
        for (int h = 0; h < 2; ++h) {
            frag_ab a0[4], a1[4];
            #pragma unroll
            for (int mi = 0; mi < 4; ++mi) {
                int row = wm + (mi + h * 4) * 16 + fr;
                a0[mi] = *(const frag_ab*)(&As[1][row * 64 + ((kq       ^ (row & 7)) * 8)]);
                a1[mi] = *(const frag_ab*)(&As[1][row * 64 + (((4 + kq) ^ (row & 7)) * 8)]);
            }
            __builtin_amdgcn_s_setprio(1);
            #pragma unroll
            for (int mi = 0; mi < 4; ++mi)
                #pragma unroll
                for (int ni = 0; ni < 4; ++ni) {
                    acc[mi + h * 4][ni] = __builtin_amdgcn_mfma_f32_16x16x32_bf16(a0[mi], b0[ni], acc[mi + h * 4][ni], 0, 0, 0);
                    acc[mi + h * 4][ni] = __builtin_amdgcn_mfma_f32_16x16x32_bf16(a1[mi], b1[ni], acc[mi + h * 4][ni], 0, 0, 0);
                }
            __builtin_amdgcn_s_setprio(0);
        }
    }

    // epilogue
    const int colb = lane & 15, rb = (lane >> 4) * 4;
    #pragma unroll
    for (int ni = 0; ni < 4; ++ni) {
        const int col = n0 + wn + ni * 16 + colb;
        const float bias = bo[col];
        #pragma unroll
        for (int mi = 0; mi < 8; ++mi) {
            #pragma unroll
            for (int r = 0; r < 4; ++r) {
                const int row = m0 + wm + mi * 16 + rb + r;
                out[(size_t)row * DIM + col] = acc[mi][ni][r] + bias;
            }
        }
    }
}

// ---------- launch ----------
extern "C" void kernel_launch(void* const* d_in, const int* in_sizes, int n_in,
                              void* d_out, int out_size, void* d_ws, size_t ws_size,
                              hipStream_t stream) {
    const float* x  = (const float*)d_in[0];
    const float* w2 = (const float*)d_in[1];
    const float* b2 = (const float*)d_in[2];
    const float* wo = (const float*)d_in[3];
    const float* bo = (const float*)d_in[4];
    float* out = (float*)d_out;

    char* ws = (char*)d_ws;
    unsigned short* wob = (unsigned short*)ws;                       // 2 MB
    unsigned short* ybf = (unsigned short*)(ws + 2097152);           // 32 MB
    unsigned short* w2p = (unsigned short*)(ws + 2097152 + 33554432);// 192 KB

    cvt_w2_kernel<<<48, 256, 0, stream>>>(w2, w2p);
    att_y_kernel<<<2048, 256, 0, stream>>>(x, w2p, b2, wo, ybf, wob);
    gemm_kernel<<<NTOK / GBM * (DIM / GBN), 512, 0, stream>>>(ybf, wob, bo, out);
}